// Round 7
// baseline (1037.659 us; speedup 1.0000x reference)
//
#include <hip/hip_runtime.h>
#include <cstdint>

// GRUMessage on MI355X — single-plane bf16 MFMA, batch-chunked for unknown ws_size.
// B=16, R=1024, F=I=1024, 3F=3072, M=B*R=16384, ITERS=2.
//
// Round-5 evidence: absmax == max|ref| => out never written => ws_size guard
// tripped at ~350MB. ws_size is unknown; this version adapts: the pipeline is
// per-batch separable (the sum-aggregation is within-batch), so we process
// chunks of NB batches with NB chosen at runtime (largest of 16,8,4,2,1 that
// fits). Footprint = ~16.5MB fixed + 6*NB MB (A, X, Hbf planes).
//
// Algebra: inp = (sum_r x - x)/1023  =>  gi = t/1023 + x @ (-w_ih/1023)^T + b_ih
// where t[b,g] = (sum_r x[b,r,:]) . w_ih[g,:]  (fp32, tiny).
// k_gates fuses r/z/n GEMMs + GRU update per 128x128 tile:
//   ar/az over K=2048 (x|h vs [-w_ih/1023 | w_hh] r/z rows),
//   ani over K=1024 (x vs -w_ih_n/1023), anh over K=1024 (h vs w_hh_n).
// h passthrough (z*h) and k_apass read the exact fp32 h (features / out).

typedef unsigned short u16;
typedef short   vshort8 __attribute__((ext_vector_type(8)));
typedef float   vfloat4 __attribute__((ext_vector_type(4)));
typedef u16     vu16x4  __attribute__((ext_vector_type(4)));
typedef u16     vu16x8  __attribute__((ext_vector_type(8)));

#define DEVI __device__ __forceinline__

DEVI u16 f2bf(float f) {
  uint32_t u = __float_as_uint(f);
  u += 0x7FFFu + ((u >> 16) & 1u);   // round-to-nearest-even
  return (u16)(u >> 16);
}
DEVI float bf2f(u16 h) { return __uint_as_float(((uint32_t)h) << 16); }
DEVI float sigm(float x) { return 1.0f / (1.0f + __expf(-x)); }
DEVI float tanh_(float x) {
  float ax = fabsf(x);
  float e  = __expf(-2.0f * ax);
  float t  = (1.0f - e) / (1.0f + e);
  return x < 0.0f ? -t : t;
}
DEVI vfloat4 mfma_bf16(vshort8 a, vshort8 b, vfloat4 c) {
  return __builtin_amdgcn_mfma_f32_16x16x32_bf16(a, b, c, 0, 0, 0);
}
DEVI void gl16(const void* g, void* l) {
  __builtin_amdgcn_global_load_lds(
      (__attribute__((address_space(1))) void*)(void*)g,
      (__attribute__((address_space(3))) void*)l, 16, 0, 0);
}

// ---------------- conversion kernels ----------------

// fp32 -> bf16, 4 elems/thread
__global__ __launch_bounds__(256) void k_cvt4(const float* __restrict__ in,
                                              u16* __restrict__ outp, int n4) {
  int i = blockIdx.x * 256 + threadIdx.x;
  if (i >= n4) return;
  const float4 v = ((const float4*)in)[i];
  vu16x4 o; o[0] = f2bf(v.x); o[1] = f2bf(v.y); o[2] = f2bf(v.z); o[3] = f2bf(v.w);
  *(vu16x4*)(outp + (size_t)i * 4) = o;
}

// Wcat[g, 0:1024] = -w_ih[g,:]/1023 ; Wcat[g, 1024:2048] = w_hh[g,:]  (g < 2048)
__global__ __launch_bounds__(256) void k_wcat(const float* __restrict__ wih,
                                              const float* __restrict__ whh,
                                              u16* __restrict__ wc) {
  int i = blockIdx.x * 256 + threadIdx.x;       // < 2048*512
  const int g = i >> 9, j4 = (i & 511) << 2;
  float4 v; float s;
  if (j4 < 1024) { v = *(const float4*)&wih[((size_t)g << 10) + j4]; s = -1.0f / 1023.0f; }
  else           { v = *(const float4*)&whh[((size_t)g << 10) + (j4 - 1024)]; s = 1.0f; }
  vu16x4 o;
  o[0] = f2bf(v.x * s); o[1] = f2bf(v.y * s); o[2] = f2bf(v.z * s); o[3] = f2bf(v.w * s);
  *(vu16x4*)(wc + (size_t)g * 2048 + j4) = o;
}

// Wni = -w_ih[2048+gg,:]/1023 ; Wnh = w_hh[2048+gg,:]   (gg < 1024)
__global__ __launch_bounds__(256) void k_wn(const float* __restrict__ wih,
                                            const float* __restrict__ whh,
                                            u16* __restrict__ wni, u16* __restrict__ wnh) {
  int i = blockIdx.x * 256 + threadIdx.x;       // < 1024*256
  const int gg = i >> 8, j4 = (i & 255) << 2;
  const size_t src = ((size_t)(2048 + gg) << 10) + j4;
  const size_t dst = ((size_t)gg << 10) + j4;
  const float4 a = *(const float4*)&wih[src];
  const float4 b = *(const float4*)&whh[src];
  const float s = -1.0f / 1023.0f;
  vu16x4 oi, oh;
  oi[0] = f2bf(a.x * s); oi[1] = f2bf(a.y * s); oi[2] = f2bf(a.z * s); oi[3] = f2bf(a.w * s);
  oh[0] = f2bf(b.x);     oh[1] = f2bf(b.y);     oh[2] = f2bf(b.z);     oh[3] = f2bf(b.w);
  *(vu16x4*)(wni + dst) = oi;
  *(vu16x4*)(wnh + dst) = oh;
}

// a = relu(h * box_feat); chunk-local (H, boxes pre-offset). grid = NB*512.
__global__ __launch_bounds__(256) void k_apass(const float* __restrict__ H,
                                               const float* __restrict__ boxes,
                                               const float* __restrict__ bw, const float* __restrict__ bb,
                                               u16* __restrict__ A) {
  const int T = blockIdx.x * 256 + threadIdx.x;   // < NB*1024*128
  const int m = T >> 7;
  const int f0 = (T & 127) << 3;
  const size_t o = ((size_t)m << 10) + f0;
  const float4 bx = *(const float4*)&boxes[(size_t)m << 2];
  const float4 h0 = *(const float4*)&H[o];
  const float4 h1 = *(const float4*)&H[o + 4];
  const float hv[8] = {h0.x, h0.y, h0.z, h0.w, h1.x, h1.y, h1.z, h1.w};
  vu16x8 oa;
#pragma unroll
  for (int j = 0; j < 8; ++j) {
    const int f = f0 + j;
    const float4 wv = *(const float4*)&bw[(size_t)f << 2];
    const float bfv = bb[f] + bx.x * wv.x + bx.y * wv.y + bx.z * wv.z + bx.w * wv.w;
    float a = hv[j] * bfv;
    oa[j] = f2bf(a > 0.0f ? a : 0.0f);
  }
  *(vu16x8*)(A + o) = oa;
}

// ---------------- reductions (chunk-local): s[b,i] = sum_r x[b,r,i]; t = s.w_ih^T ----

__global__ __launch_bounds__(256) void k_sred1(const u16* __restrict__ X,
                                               float* __restrict__ part) {
  const int b = blockIdx.x, ch = blockIdx.y;  // NB x 32
  const int r0 = ch << 5;
  const int c4 = threadIdx.x << 2;
  float a0 = 0, a1 = 0, a2 = 0, a3 = 0;
  for (int r = 0; r < 32; ++r) {
    const size_t base = ((size_t)((b << 10) + r0 + r) << 10) + c4;
    const vu16x4 v = *(const vu16x4*)(X + base);
    a0 += bf2f(v[0]); a1 += bf2f(v[1]); a2 += bf2f(v[2]); a3 += bf2f(v[3]);
  }
  const size_t pb = ((size_t)((b << 5) + ch) << 10) + c4;
  float4 o; o.x = a0; o.y = a1; o.z = a2; o.w = a3;
  *(float4*)(part + pb) = o;
}

__global__ __launch_bounds__(256) void k_sred2(const float* __restrict__ part, float* __restrict__ s) {
  const int i = blockIdx.x * 256 + threadIdx.x;  // < NB*1024
  const int b = i >> 10, col = i & 1023;
  float a = 0;
  for (int ch = 0; ch < 32; ++ch) a += part[((size_t)((b << 5) + ch) << 10) + col];
  s[i] = a;
}

// computes all 16 local slots; only slots < NB are meaningful (rest garbage, unread)
__global__ __launch_bounds__(256) void k_t(const float* __restrict__ s, const float* __restrict__ wih,
                                           float* __restrict__ t) {
  const int g = blockIdx.x;                     // < 3072
  const int tid = threadIdx.x, lane = tid & 63, w = tid >> 6;
  float acc[16];
#pragma unroll
  for (int b = 0; b < 16; ++b) acc[b] = 0.0f;
  for (int i = tid; i < 1024; i += 256) {
    const float wv = wih[((size_t)g << 10) + i];
#pragma unroll
    for (int b = 0; b < 16; ++b) acc[b] += s[(b << 10) + i] * wv;
  }
  __shared__ float red[16][4];
#pragma unroll
  for (int b = 0; b < 16; ++b) {
    float v = acc[b];
    for (int off = 32; off > 0; off >>= 1) v += __shfl_down(v, off);
    if (lane == 0) red[b][w] = v;
  }
  __syncthreads();
  if (tid < 16) t[tid * 3072 + g] = red[tid][0] + red[tid][1] + red[tid][2] + red[tid][3];
}

// ---------------- x = a . fc_input_w^T + b  (chunk: M=NB*1024, N=1024, K=1024) ----------
// grid = NB*64 (m-blocks = NB*8, n-blocks = 8)

__global__ __launch_bounds__(256) void k_gemm_x(
    const u16* __restrict__ A, const u16* __restrict__ B,
    const float* __restrict__ bias, u16* __restrict__ X) {
  __shared__ u16 As[4096], Bs[4096];
  const int tid = threadIdx.x, w = tid >> 6, lane = tid & 63;
  const int bm0 = (blockIdx.x >> 3) << 7;
  const int bn0 = (blockIdx.x & 7) << 7;
  const int wr = w >> 1, wc = w & 1;
  const int row16 = lane & 15, k8 = (lane >> 4) << 3;
  vfloat4 acc[4][4] = {};

  for (int kt = 0; kt < 32; ++kt) {
    const int k0 = kt << 5;
    __syncthreads();
#pragma unroll
    for (int r = 0; r < 2; ++r) {
      const int cbase = (w << 6) + (r << 8);
      const int c = cbase + lane;
      const int rowT = c >> 2, col8 = (c & 3) << 3;
      const int eo = cbase << 3;
      gl16(A + (size_t)(bm0 + rowT) * 1024 + (k0 + col8), As + eo);
      gl16(B + (size_t)(bn0 + rowT) * 1024 + (k0 + col8), Bs + eo);
    }
    __syncthreads();
    vshort8 af[4], bf[4];
#pragma unroll
    for (int mf = 0; mf < 4; ++mf)
      af[mf] = *(const vshort8*)(As + (((wr << 6) + (mf << 4) + row16) << 5) + k8);
#pragma unroll
    for (int nf = 0; nf < 4; ++nf)
      bf[nf] = *(const vshort8*)(Bs + (((wc << 6) + (nf << 4) + row16) << 5) + k8);
#pragma unroll
    for (int mf = 0; mf < 4; ++mf)
#pragma unroll
      for (int nf = 0; nf < 4; ++nf)
        acc[mf][nf] = mfma_bf16(af[mf], bf[nf], acc[mf][nf]);
  }
#pragma unroll
  for (int mf = 0; mf < 4; ++mf)
#pragma unroll
    for (int nf = 0; nf < 4; ++nf) {
      const int gcol = bn0 + (wc << 6) + (nf << 4) + row16;
      const int grow0 = bm0 + (wr << 6) + (mf << 4) + ((lane >> 4) << 2);
      const float bv = bias[gcol];
#pragma unroll
      for (int rg = 0; rg < 4; ++rg)
        X[(size_t)(grow0 + rg) * 1024 + gcol] = f2bf(acc[mf][nf][rg] + bv);
    }
}

// ---------------- fused gates + GRU update (chunk-local) ----------------
// Output tile 128m x 128gg, 8 waves (2m x 4gg), 512 threads. grid = NB*64.
__global__ __launch_bounds__(512) void k_gates(
    const u16* __restrict__ X, const u16* __restrict__ Hbf,
    const float* __restrict__ Hsrc,
    const u16* __restrict__ Wcat, const u16* __restrict__ Wni, const u16* __restrict__ Wnh,
    const float* __restrict__ tbuf, const float* __restrict__ bih, const float* __restrict__ bhh,
    float* __restrict__ out) {
  __shared__ u16 As[4096], Br[4096], Bz[4096], Bn[4096];
  const int tid = threadIdx.x, w = tid >> 6, lane = tid & 63;
  const int cpx = gridDim.x >> 3;                                 // gridDim.x % 8 == 0
  const int swz = (blockIdx.x & 7) * cpx + (blockIdx.x >> 3);     // bijective XCD swizzle
  const int bm0 = (swz >> 3) << 7;    // NB*8 m-tiles
  const int bn0 = (swz & 7) << 7;     // 8 gg-tiles
  const int wm = w >> 2, wn = w & 3;
  const int row16 = lane & 15, k8 = (lane >> 4) << 3;
  const int cbase = w << 6;
  const int c = cbase + lane;
  const int rowT = c >> 2, col8 = (c & 3) << 3;
  const int eo = cbase << 3;          // wave-uniform LDS base (u16 units)

  vfloat4 ar[4][2] = {}, az[4][2] = {}, ani[4][2] = {}, anh[4][2] = {};

  // half 0: A = x, Bn = Wni (k 0..1023)
#pragma unroll 1
  for (int kt = 0; kt < 32; ++kt) {
    const int kk = kt << 5;
    __syncthreads();
    gl16(X    + (size_t)(bm0 + rowT) * 1024 + kk + col8, As + eo);
    gl16(Wcat + (size_t)(bn0 + rowT) * 2048 + kk + col8, Br + eo);
    gl16(Wcat + (size_t)(1024 + bn0 + rowT) * 2048 + kk + col8, Bz + eo);
    gl16(Wni  + (size_t)(bn0 + rowT) * 1024 + kk + col8, Bn + eo);
    __syncthreads();
    vshort8 af[4], br[2], bz[2], bn[2];
#pragma unroll
    for (int mf = 0; mf < 4; ++mf)
      af[mf] = *(const vshort8*)(As + (((wm << 6) + (mf << 4) + row16) << 5) + k8);
#pragma unroll
    for (int nf = 0; nf < 2; ++nf) {
      const int rB = (((wn << 5) + (nf << 4) + row16) << 5) + k8;
      br[nf] = *(const vshort8*)(Br + rB);
      bz[nf] = *(const vshort8*)(Bz + rB);
      bn[nf] = *(const vshort8*)(Bn + rB);
    }
#pragma unroll
    for (int mf = 0; mf < 4; ++mf)
#pragma unroll
      for (int nf = 0; nf < 2; ++nf) {
        ar[mf][nf]  = mfma_bf16(af[mf], br[nf], ar[mf][nf]);
        az[mf][nf]  = mfma_bf16(af[mf], bz[nf], az[mf][nf]);
        ani[mf][nf] = mfma_bf16(af[mf], bn[nf], ani[mf][nf]);
      }
  }
  // half 1: A = h, Bn = Wnh (Wcat k 1024..2047)
#pragma unroll 1
  for (int kt = 0; kt < 32; ++kt) {
    const int kk = kt << 5;
    const int k0 = 1024 + kk;
    __syncthreads();
    gl16(Hbf  + (size_t)(bm0 + rowT) * 1024 + kk + col8, As + eo);
    gl16(Wcat + (size_t)(bn0 + rowT) * 2048 + k0 + col8, Br + eo);
    gl16(Wcat + (size_t)(1024 + bn0 + rowT) * 2048 + k0 + col8, Bz + eo);
    gl16(Wnh  + (size_t)(bn0 + rowT) * 1024 + kk + col8, Bn + eo);
    __syncthreads();
    vshort8 af[4], br[2], bz[2], bn[2];
#pragma unroll
    for (int mf = 0; mf < 4; ++mf)
      af[mf] = *(const vshort8*)(As + (((wm << 6) + (mf << 4) + row16) << 5) + k8);
#pragma unroll
    for (int nf = 0; nf < 2; ++nf) {
      const int rB = (((wn << 5) + (nf << 4) + row16) << 5) + k8;
      br[nf] = *(const vshort8*)(Br + rB);
      bz[nf] = *(const vshort8*)(Bz + rB);
      bn[nf] = *(const vshort8*)(Bn + rB);
    }
#pragma unroll
    for (int mf = 0; mf < 4; ++mf)
#pragma unroll
      for (int nf = 0; nf < 2; ++nf) {
        ar[mf][nf]  = mfma_bf16(af[mf], br[nf], ar[mf][nf]);
        az[mf][nf]  = mfma_bf16(af[mf], bz[nf], az[mf][nf]);
        anh[mf][nf] = mfma_bf16(af[mf], bn[nf], anh[mf][nf]);
      }
  }

  const float inv = 1.0f / 1023.0f;
  const int b = bm0 >> 10;   // chunk-local batch (128-row tile never crosses batches)
#pragma unroll
  for (int nf = 0; nf < 2; ++nf) {
    const int gcol = bn0 + (wn << 5) + (nf << 4) + row16;
    const float cr = tbuf[b * 3072 + gcol] * inv + bih[gcol] + bhh[gcol];
    const float cz = tbuf[b * 3072 + 1024 + gcol] * inv + bih[1024 + gcol] + bhh[1024 + gcol];
    const float ci = tbuf[b * 3072 + 2048 + gcol] * inv + bih[2048 + gcol];
    const float ch = bhh[2048 + gcol];
#pragma unroll
    for (int mf = 0; mf < 4; ++mf) {
      const int grow0 = bm0 + (wm << 6) + (mf << 4) + ((lane >> 4) << 2);
#pragma unroll
      for (int rg = 0; rg < 4; ++rg) {
        const size_t o = (size_t)(grow0 + rg) * 1024 + gcol;
        const float rv  = sigm(ar[mf][nf][rg] + cr);
        const float zv  = sigm(az[mf][nf][rg] + cz);
        const float i_n = ani[mf][nf][rg] + ci;
        const float h_n = anh[mf][nf][rg] + ch;
        const float nv  = tanh_(i_n + rv * h_n);
        out[o] = (1.0f - zv) * nv + zv * Hsrc[o];
      }
    }
  }
}

// ---------------- host ----------------

extern "C" void kernel_launch(void* const* d_in, const int* in_sizes, int n_in,
                              void* d_out, int out_size, void* d_ws, size_t ws_size,
                              hipStream_t stream) {
  const float* features   = (const float*)d_in[0];
  const float* boxes      = (const float*)d_in[1];
  const float* fc_box_w   = (const float*)d_in[2];
  const float* fc_box_b   = (const float*)d_in[3];
  const float* fc_input_w = (const float*)d_in[4];
  const float* fc_input_b = (const float*)d_in[5];
  const float* w_ih       = (const float*)d_in[6];
  const float* w_hh       = (const float*)d_in[7];
  const float* b_ih       = (const float*)d_in[8];
  const float* b_hh       = (const float*)d_in[9];
  float* out = (float*)d_out;

  // choose NB (batches per chunk), then allocate
  u16 *fcw, *wcat, *wni, *wnh, *A, *X, *Hbf;
  float *part, *sbuf, *tbuf;
  int NB = 16;
  for (;; NB >>= 1) {
    if (NB == 0) return;   // ws too small even for NB=1 (validation will fail loudly)
    char* base = (char*)d_ws;
    size_t off = 0;
    auto take = [&](size_t bytes) -> char* {
      char* q = base + off;
      off += (bytes + 255) & ~(size_t)255;
      return q;
    };
    const size_t CPLANE = (size_t)NB * 1024 * 1024 * 2;   // chunk bf16 plane
    fcw  = (u16*)take((size_t)1024 * 1024 * 2);
    wcat = (u16*)take((size_t)2048 * 2048 * 2);
    wni  = (u16*)take((size_t)1024 * 1024 * 2);
    wnh  = (u16*)take((size_t)1024 * 1024 * 2);
    part = (float*)take((size_t)16 * 32 * 1024 * 4);
    sbuf = (float*)take((size_t)16 * 1024 * 4);
    tbuf = (float*)take((size_t)16 * 3072 * 4);
    A    = (u16*)take(CPLANE);
    X    = (u16*)take(CPLANE);
    Hbf  = (u16*)take(CPLANE);
    if (off <= ws_size) break;
  }
  const int NCH = 16 / NB;

  // weight conversions (identical work every call)
  k_cvt4<<<1024, 256, 0, stream>>>(fc_input_w, fcw, 262144);
  k_wcat<<<4096, 256, 0, stream>>>(w_ih, w_hh, wcat);
  k_wn<<<1024, 256, 0, stream>>>(w_ih, w_hh, wni, wnh);

  for (int it = 0; it < 2; ++it) {
    const float* Hfull = it ? (const float*)out : features;   // exact fp32 h
    for (int cc = 0; cc < NCH; ++cc) {
      const size_t m0 = (size_t)cc * NB * 1024;
      const float* Hsrc = Hfull + m0 * 1024;
      k_apass<<<NB * 512, 256, 0, stream>>>(Hsrc, boxes + m0 * 4,
                                            fc_box_w, fc_box_b, A);
      k_gemm_x<<<NB * 64, 256, 0, stream>>>(A, fcw, fc_input_b, X);
      k_sred1<<<dim3(NB, 32), 256, 0, stream>>>(X, part);
      k_sred2<<<NB * 4, 256, 0, stream>>>(part, sbuf);
      k_t<<<3072, 256, 0, stream>>>(sbuf, w_ih, tbuf);
      k_cvt4<<<NB * 1024, 256, 0, stream>>>(Hsrc, Hbf, NB * 262144);
      k_gates<<<NB * 64, 512, 0, stream>>>(X, Hbf, Hsrc, wcat, wni, wnh,
                                           tbuf, b_ih, b_hh, out + m0 * 1024);
    }
  }
}

// Round 9
// 979.068 us; speedup vs baseline: 1.0598x; 1.0598x over previous
//
#include <hip/hip_runtime.h>
#include <cstdint>

// GRUMessage on MI355X — single-plane bf16 MFMA, batch-chunked, LDS-swizzled.
// B=16, R=1024, F=I=1024, 3F=3072, M=B*R=16384, ITERS=2.
//
// Round-7 baseline (measured): 1037us, k_gates 2x350us, SQ_LDS_BANK_CONFLICT=2.1e7
// (4-way conflict on fragment ds_read_b128 phases), MfmaUtil 24%, HBM 12%.
// Round-8/9: chunk-swizzled LDS via pre-swizzled global source (rule #21:
// linear gl16 dest + per-lane-permuted source + same XOR on read).
// Swizzle: data (row r, chunk q) at slot r*4 + (q ^ ((r>>1)&3)) -> each 8-lane
// service phase hits all 8 16B bank-groups (conflict-free). Bit-identical math.
// Also: Hbf bf16 conversion folded into k_apass (kills one 96MB pass/iter).
//
// Algebra: inp = (sum_r x - x)/1023  =>  gi = t/1023 + x @ (-w_ih/1023)^T + b_ih
// where t[b,g] = (sum_r x[b,r,:]) . w_ih[g,:]  (fp32, tiny).
// k_gates fuses r/z/n GEMMs + GRU update per 128x128 tile.
// h passthrough (z*h) and k_apass read the exact fp32 h (features / out).

typedef unsigned short u16;
typedef short   vshort8 __attribute__((ext_vector_type(8)));
typedef float   vfloat4 __attribute__((ext_vector_type(4)));
typedef u16     vu16x4  __attribute__((ext_vector_type(4)));
typedef u16     vu16x8  __attribute__((ext_vector_type(8)));

#define DEVI __device__ __forceinline__

DEVI u16 f2bf(float f) {
  uint32_t u = __float_as_uint(f);
  u += 0x7FFFu + ((u >> 16) & 1u);   // round-to-nearest-even
  return (u16)(u >> 16);
}
DEVI float bf2f(u16 h) { return __uint_as_float(((uint32_t)h) << 16); }
DEVI float sigm(float x) { return 1.0f / (1.0f + __expf(-x)); }
DEVI float tanh_(float x) {
  float ax = fabsf(x);
  float e  = __expf(-2.0f * ax);
  float t  = (1.0f - e) / (1.0f + e);
  return x < 0.0f ? -t : t;
}
DEVI vfloat4 mfma_bf16(vshort8 a, vshort8 b, vfloat4 c) {
  return __builtin_amdgcn_mfma_f32_16x16x32_bf16(a, b, c, 0, 0, 0);
}
DEVI void gl16(const void* g, void* l) {
  __builtin_amdgcn_global_load_lds(
      (__attribute__((address_space(1))) void*)(void*)g,
      (__attribute__((address_space(3))) void*)l, 16, 0, 0);
}

// ---------------- conversion kernels ----------------

__global__ __launch_bounds__(256) void k_cvt4(const float* __restrict__ in,
                                              u16* __restrict__ outp, int n4) {
  int i = blockIdx.x * 256 + threadIdx.x;
  if (i >= n4) return;
  const float4 v = ((const float4*)in)[i];
  vu16x4 o; o[0] = f2bf(v.x); o[1] = f2bf(v.y); o[2] = f2bf(v.z); o[3] = f2bf(v.w);
  *(vu16x4*)(outp + (size_t)i * 4) = o;
}

// Wcat[g, 0:1024] = -w_ih[g,:]/1023 ; Wcat[g, 1024:2048] = w_hh[g,:]  (g < 2048)
__global__ __launch_bounds__(256) void k_wcat(const float* __restrict__ wih,
                                              const float* __restrict__ whh,
                                              u16* __restrict__ wc) {
  int i = blockIdx.x * 256 + threadIdx.x;       // < 2048*512
  const int g = i >> 9, j4 = (i & 511) << 2;
  float4 v; float s;
  if (j4 < 1024) { v = *(const float4*)&wih[((size_t)g << 10) + j4]; s = -1.0f / 1023.0f; }
  else           { v = *(const float4*)&whh[((size_t)g << 10) + (j4 - 1024)]; s = 1.0f; }
  vu16x4 o;
  o[0] = f2bf(v.x * s); o[1] = f2bf(v.y * s); o[2] = f2bf(v.z * s); o[3] = f2bf(v.w * s);
  *(vu16x4*)(wc + (size_t)g * 2048 + j4) = o;
}

// Wni = -w_ih[2048+gg,:]/1023 ; Wnh = w_hh[2048+gg,:]   (gg < 1024)
__global__ __launch_bounds__(256) void k_wn(const float* __restrict__ wih,
                                            const float* __restrict__ whh,
                                            u16* __restrict__ wni, u16* __restrict__ wnh) {
  int i = blockIdx.x * 256 + threadIdx.x;       // < 1024*256
  const int gg = i >> 8, j4 = (i & 255) << 2;
  const size_t src = ((size_t)(2048 + gg) << 10) + j4;
  const size_t dst = ((size_t)gg << 10) + j4;
  const float4 a = *(const float4*)&wih[src];
  const float4 b = *(const float4*)&whh[src];
  const float s = -1.0f / 1023.0f;
  vu16x4 oi, oh;
  oi[0] = f2bf(a.x * s); oi[1] = f2bf(a.y * s); oi[2] = f2bf(a.z * s); oi[3] = f2bf(a.w * s);
  oh[0] = f2bf(b.x);     oh[1] = f2bf(b.y);     oh[2] = f2bf(b.z);     oh[3] = f2bf(b.w);
  *(vu16x4*)(wni + dst) = oi;
  *(vu16x4*)(wnh + dst) = oh;
}

// a = relu(h * box_feat), Hbf = bf16(h); chunk-local. grid = NB*512.
__global__ __launch_bounds__(256) void k_apass(const float* __restrict__ H,
                                               const float* __restrict__ boxes,
                                               const float* __restrict__ bw, const float* __restrict__ bb,
                                               u16* __restrict__ A, u16* __restrict__ Hbf) {
  const int T = blockIdx.x * 256 + threadIdx.x;   // < NB*1024*128
  const int m = T >> 7;
  const int f0 = (T & 127) << 3;
  const size_t o = ((size_t)m << 10) + f0;
  const float4 bx = *(const float4*)&boxes[(size_t)m << 2];
  const float4 h0 = *(const float4*)&H[o];
  const float4 h1 = *(const float4*)&H[o + 4];
  const float hv[8] = {h0.x, h0.y, h0.z, h0.w, h1.x, h1.y, h1.z, h1.w};
  vu16x8 oa, ohb;
#pragma unroll
  for (int j = 0; j < 8; ++j) {
    const int f = f0 + j;
    const float4 wv = *(const float4*)&bw[(size_t)f << 2];
    const float bfv = bb[f] + bx.x * wv.x + bx.y * wv.y + bx.z * wv.z + bx.w * wv.w;
    float a = hv[j] * bfv;
    oa[j] = f2bf(a > 0.0f ? a : 0.0f);
    ohb[j] = f2bf(hv[j]);
  }
  *(vu16x8*)(A + o) = oa;
  *(vu16x8*)(Hbf + o) = ohb;
}

// ---------------- reductions (chunk-local) ----------------

__global__ __launch_bounds__(256) void k_sred1(const u16* __restrict__ X,
                                               float* __restrict__ part) {
  const int b = blockIdx.x, ch = blockIdx.y;  // NB x 32
  const int r0 = ch << 5;
  const int c4 = threadIdx.x << 2;
  float a0 = 0, a1 = 0, a2 = 0, a3 = 0;
  for (int r = 0; r < 32; ++r) {
    const size_t base = ((size_t)((b << 10) + r0 + r) << 10) + c4;
    const vu16x4 v = *(const vu16x4*)(X + base);
    a0 += bf2f(v[0]); a1 += bf2f(v[1]); a2 += bf2f(v[2]); a3 += bf2f(v[3]);
  }
  const size_t pb = ((size_t)((b << 5) + ch) << 10) + c4;
  float4 o; o.x = a0; o.y = a1; o.z = a2; o.w = a3;
  *(float4*)(part + pb) = o;
}

__global__ __launch_bounds__(256) void k_sred2(const float* __restrict__ part, float* __restrict__ s) {
  const int i = blockIdx.x * 256 + threadIdx.x;  // < NB*1024
  const int b = i >> 10, col = i & 1023;
  float a = 0;
  for (int ch = 0; ch < 32; ++ch) a += part[((size_t)((b << 5) + ch) << 10) + col];
  s[i] = a;
}

__global__ __launch_bounds__(256) void k_t(const float* __restrict__ s, const float* __restrict__ wih,
                                           float* __restrict__ t) {
  const int g = blockIdx.x;                     // < 3072
  const int tid = threadIdx.x, lane = tid & 63, w = tid >> 6;
  float acc[16];
#pragma unroll
  for (int b = 0; b < 16; ++b) acc[b] = 0.0f;
  for (int i = tid; i < 1024; i += 256) {
    const float wv = wih[((size_t)g << 10) + i];
#pragma unroll
    for (int b = 0; b < 16; ++b) acc[b] += s[(b << 10) + i] * wv;
  }
  __shared__ float red[16][4];
#pragma unroll
  for (int b = 0; b < 16; ++b) {
    float v = acc[b];
    for (int off = 32; off > 0; off >>= 1) v += __shfl_down(v, off);
    if (lane == 0) red[b][w] = v;
  }
  __syncthreads();
  if (tid < 16) t[tid * 3072 + g] = red[tid][0] + red[tid][1] + red[tid][2] + red[tid][3];
}

// ---------------- x = a . fc_input_w^T + b  (chunk: M=NB*1024, N=1024, K=1024) ----------
// LDS tile swizzle: data (row r, 16B-chunk q) at slot r*4 + (q ^ ((r>>1)&3)).
// Write: lane c (slot c) loads global chunk (c&3)^((c>>3)&3).
// Read: k-chunk q fetched at chunk (q ^ ((row16>>1)&3)) of the row.

__global__ __launch_bounds__(256) void k_gemm_x(
    const u16* __restrict__ A, const u16* __restrict__ B,
    const float* __restrict__ bias, u16* __restrict__ X) {
  __shared__ u16 As[4096], Bs[4096];
  const int tid = threadIdx.x, w = tid >> 6, lane = tid & 63;
  const int bm0 = (blockIdx.x >> 3) << 7;
  const int bn0 = (blockIdx.x & 7) << 7;
  const int wr = w >> 1, wc = w & 1;
  const int row16 = lane & 15;
  const int k8s = (((lane >> 4) ^ ((row16 >> 1) & 3)) << 3);   // swizzled read chunk
  vfloat4 acc[4][4] = {};

  for (int kt = 0; kt < 32; ++kt) {
    const int k0 = kt << 5;
    __syncthreads();
#pragma unroll
    for (int r = 0; r < 2; ++r) {
      const int cbase = (w << 6) + (r << 8);
      const int c = cbase + lane;
      const int rowT = c >> 2;
      const int col8 = (((c & 3) ^ ((c >> 3) & 3)) << 3);       // pre-swizzled source
      const int eo = cbase << 3;
      gl16(A + (size_t)(bm0 + rowT) * 1024 + (k0 + col8), As + eo);
      gl16(B + (size_t)(bn0 + rowT) * 1024 + (k0 + col8), Bs + eo);
    }
    __syncthreads();
    vshort8 af[4], bf[4];
#pragma unroll
    for (int mf = 0; mf < 4; ++mf)
      af[mf] = *(const vshort8*)(As + (((wr << 6) + (mf << 4) + row16) << 5) + k8s);
#pragma unroll
    for (int nf = 0; nf < 4; ++nf)
      bf[nf] = *(const vshort8*)(Bs + (((wc << 6) + (nf << 4) + row16) << 5) + k8s);
#pragma unroll
    for (int mf = 0; mf < 4; ++mf)
#pragma unroll
      for (int nf = 0; nf < 4; ++nf)
        acc[mf][nf] = mfma_bf16(af[mf], bf[nf], acc[mf][nf]);
  }
#pragma unroll
  for (int mf = 0; mf < 4; ++mf)
#pragma unroll
    for (int nf = 0; nf < 4; ++nf) {
      const int gcol = bn0 + (wc << 6) + (nf << 4) + row16;
      const int grow0 = bm0 + (wr << 6) + (mf << 4) + ((lane >> 4) << 2);
      const float bv = bias[gcol];
#pragma unroll
      for (int rg = 0; rg < 4; ++rg)
        X[(size_t)(grow0 + rg) * 1024 + gcol] = f2bf(acc[mf][nf][rg] + bv);
    }
}

// ---------------- fused gates + GRU update (chunk-local, swizzled LDS) ----------------
// Output tile 128m x 128gg, 8 waves (2m x 4gg), 512 threads. grid = NB*64.
__global__ __launch_bounds__(512) void k_gates(
    const u16* __restrict__ X, const u16* __restrict__ Hbf,
    const float* __restrict__ Hsrc,
    const u16* __restrict__ Wcat, const u16* __restrict__ Wni, const u16* __restrict__ Wnh,
    const float* __restrict__ tbuf, const float* __restrict__ bih, const float* __restrict__ bhh,
    float* __restrict__ out) {
  __shared__ u16 As[4096], Br[4096], Bz[4096], Bn[4096];
  const int tid = threadIdx.x, w = tid >> 6, lane = tid & 63;
  const int cpx = gridDim.x >> 3;                                 // gridDim.x % 8 == 0
  const int swz = (blockIdx.x & 7) * cpx + (blockIdx.x >> 3);     // bijective XCD swizzle
  const int bm0 = (swz >> 3) << 7;    // NB*8 m-tiles
  const int bn0 = (swz & 7) << 7;     // 8 gg-tiles
  const int wm = w >> 2, wn = w & 3;
  const int row16 = lane & 15;
  const int k8s = (((lane >> 4) ^ ((row16 >> 1) & 3)) << 3);      // swizzled read chunk
  const int cbase = w << 6;
  const int c = cbase + lane;
  const int rowT = c >> 2;
  const int col8 = (((c & 3) ^ ((c >> 3) & 3)) << 3);             // pre-swizzled source
  const int eo = cbase << 3;          // wave-uniform LDS base (u16 units)

  vfloat4 ar[4][2] = {}, az[4][2] = {}, ani[4][2] = {}, anh[4][2] = {};

  // half 0: A = x, Bn = Wni (k 0..1023)
#pragma unroll 1
  for (int kt = 0; kt < 32; ++kt) {
    const int kk = kt << 5;
    __syncthreads();
    gl16(X    + (size_t)(bm0 + rowT) * 1024 + kk + col8, As + eo);
    gl16(Wcat + (size_t)(bn0 + rowT) * 2048 + kk + col8, Br + eo);
    gl16(Wcat + (size_t)(1024 + bn0 + rowT) * 2048 + kk + col8, Bz + eo);
    gl16(Wni  + (size_t)(bn0 + rowT) * 1024 + kk + col8, Bn + eo);
    __syncthreads();
    vshort8 af[4], br[2], bz[2], bn[2];
#pragma unroll
    for (int mf = 0; mf < 4; ++mf)
      af[mf] = *(const vshort8*)(As + (((wm << 6) + (mf << 4) + row16) << 5) + k8s);
#pragma unroll
    for (int nf = 0; nf < 2; ++nf) {
      const int rB = (((wn << 5) + (nf << 4) + row16) << 5) + k8s;
      br[nf] = *(const vshort8*)(Br + rB);
      bz[nf] = *(const vshort8*)(Bz + rB);
      bn[nf] = *(const vshort8*)(Bn + rB);
    }
#pragma unroll
    for (int mf = 0; mf < 4; ++mf)
#pragma unroll
      for (int nf = 0; nf < 2; ++nf) {
        ar[mf][nf]  = mfma_bf16(af[mf], br[nf], ar[mf][nf]);
        az[mf][nf]  = mfma_bf16(af[mf], bz[nf], az[mf][nf]);
        ani[mf][nf] = mfma_bf16(af[mf], bn[nf], ani[mf][nf]);
      }
  }
  // half 1: A = h, Bn = Wnh (Wcat k 1024..2047)
#pragma unroll 1
  for (int kt = 0; kt < 32; ++kt) {
    const int kk = kt << 5;
    const int k0 = 1024 + kk;
    __syncthreads();
    gl16(Hbf  + (size_t)(bm0 + rowT) * 1024 + kk + col8, As + eo);
    gl16(Wcat + (size_t)(bn0 + rowT) * 2048 + k0 + col8, Br + eo);
    gl16(Wcat + (size_t)(1024 + bn0 + rowT) * 2048 + k0 + col8, Bz + eo);
    gl16(Wnh  + (size_t)(bn0 + rowT) * 1024 + kk + col8, Bn + eo);
    __syncthreads();
    vshort8 af[4], br[2], bz[2], bn[2];
#pragma unroll
    for (int mf = 0; mf < 4; ++mf)
      af[mf] = *(const vshort8*)(As + (((wm << 6) + (mf << 4) + row16) << 5) + k8s);
#pragma unroll
    for (int nf = 0; nf < 2; ++nf) {
      const int rB = (((wn << 5) + (nf << 4) + row16) << 5) + k8s;
      br[nf] = *(const vshort8*)(Br + rB);
      bz[nf] = *(const vshort8*)(Bz + rB);
      bn[nf] = *(const vshort8*)(Bn + rB);
    }
#pragma unroll
    for (int mf = 0; mf < 4; ++mf)
#pragma unroll
      for (int nf = 0; nf < 2; ++nf) {
        ar[mf][nf]  = mfma_bf16(af[mf], br[nf], ar[mf][nf]);
        az[mf][nf]  = mfma_bf16(af[mf], bz[nf], az[mf][nf]);
        anh[mf][nf] = mfma_bf16(af[mf], bn[nf], anh[mf][nf]);
      }
  }

  const float inv = 1.0f / 1023.0f;
  const int b = bm0 >> 10;   // chunk-local batch (128-row tile never crosses batches)
#pragma unroll
  for (int nf = 0; nf < 2; ++nf) {
    const int gcol = bn0 + (wn << 5) + (nf << 4) + row16;
    const float cr = tbuf[b * 3072 + gcol] * inv + bih[gcol] + bhh[gcol];
    const float cz = tbuf[b * 3072 + 1024 + gcol] * inv + bih[1024 + gcol] + bhh[1024 + gcol];
    const float ci = tbuf[b * 3072 + 2048 + gcol] * inv + bih[2048 + gcol];
    const float ch = bhh[2048 + gcol];
#pragma unroll
    for (int mf = 0; mf < 4; ++mf) {
      const int grow0 = bm0 + (wm << 6) + (mf << 4) + ((lane >> 4) << 2);
#pragma unroll
      for (int rg = 0; rg < 4; ++rg) {
        const size_t o = (size_t)(grow0 + rg) * 1024 + gcol;
        const float rv  = sigm(ar[mf][nf][rg] + cr);
        const float zv  = sigm(az[mf][nf][rg] + cz);
        const float i_n = ani[mf][nf][rg] + ci;
        const float h_n = anh[mf][nf][rg] + ch;
        const float nv  = tanh_(i_n + rv * h_n);
        out[o] = (1.0f - zv) * nv + zv * Hsrc[o];
      }
    }
  }
}

// ---------------- host ----------------

extern "C" void kernel_launch(void* const* d_in, const int* in_sizes, int n_in,
                              void* d_out, int out_size, void* d_ws, size_t ws_size,
                              hipStream_t stream) {
  const float* features   = (const float*)d_in[0];
  const float* boxes      = (const float*)d_in[1];
  const float* fc_box_w   = (const float*)d_in[2];
  const float* fc_box_b   = (const float*)d_in[3];
  const float* fc_input_w = (const float*)d_in[4];
  const float* fc_input_b = (const float*)d_in[5];
  const float* w_ih       = (const float*)d_in[6];
  const float* w_hh       = (const float*)d_in[7];
  const float* b_ih       = (const float*)d_in[8];
  const float* b_hh       = (const float*)d_in[9];
  float* out = (float*)d_out;

  // choose NB (batches per chunk), then allocate
  u16 *fcw, *wcat, *wni, *wnh, *A, *X, *Hbf;
  float *part, *sbuf, *tbuf;
  int NB = 16;
  for (;; NB >>= 1) {
    if (NB == 0) return;   // ws too small even for NB=1 (validation will fail loudly)
    char* base = (char*)d_ws;
    size_t off = 0;
    auto take = [&](size_t bytes) -> char* {
      char* q = base + off;
      off += (bytes + 255) & ~(size_t)255;
      return q;
    };
    const size_t CPLANE = (size_t)NB * 1024 * 1024 * 2;   // chunk bf16 plane
    fcw  = (u16*)take((size_t)1024 * 1024 * 2);
    wcat = (u16*)take((size_t)2048 * 2048 * 2);
    wni  = (u16*)take((size_t)1024 * 1024 * 2);
    wnh  = (u16*)take((size_t)1024 * 1024 * 2);
    part = (float*)take((size_t)16 * 32 * 1024 * 4);
    sbuf = (float*)take((size_t)16 * 1024 * 4);
    tbuf = (float*)take((size_t)16 * 3072 * 4);
    A    = (u16*)take(CPLANE);
    X    = (u16*)take(CPLANE);
    Hbf  = (u16*)take(CPLANE);
    if (off <= ws_size) break;
  }
  const int NCH = 16 / NB;

  // weight conversions (identical work every call)
  k_cvt4<<<1024, 256, 0, stream>>>(fc_input_w, fcw, 262144);
  k_wcat<<<4096, 256, 0, stream>>>(w_ih, w_hh, wcat);
  k_wn<<<1024, 256, 0, stream>>>(w_ih, w_hh, wni, wnh);

  for (int it = 0; it < 2; ++it) {
    const float* Hfull = it ? (const float*)out : features;   // exact fp32 h
    for (int cc = 0; cc < NCH; ++cc) {
      const size_t m0 = (size_t)cc * NB * 1024;
      const float* Hsrc = Hfull + m0 * 1024;
      k_apass<<<NB * 512, 256, 0, stream>>>(Hsrc, boxes + m0 * 4,
                                            fc_box_w, fc_box_b, A, Hbf);
      k_gemm_x<<<NB * 64, 256, 0, stream>>>(A, fcw, fc_input_b, X);
      k_sred1<<<dim3(NB, 32), 256, 0, stream>>>(X, part);
      k_sred2<<<NB * 4, 256, 0, stream>>>(part, sbuf);
      k_t<<<3072, 256, 0, stream>>>(sbuf, w_ih, tbuf);
      k_gates<<<NB * 64, 512, 0, stream>>>(X, Hbf, Hsrc, wcat, wni, wnh,
                                           tbuf, b_ih, b_hh, out + m0 * 1024);
    }
  }
}